// Round 8
// baseline (287.652 us; speedup 1.0000x reference)
//
#include <hip/hip_runtime.h>
#include <cstddef>
#include <cstdint>

#define T_TOK 2048
#define HD 1024
#define ID 1024
#define NE 16
#define TOPK 4
#define BM 128
#define BN 128
#define BK 32
#define NK1 (HD / BK)
#define MT_MAX 96
#define SLOT_CAP (MT_MAX * BM)

typedef float f32x4 __attribute__((ext_vector_type(4)));
typedef __bf16 bf16x8 __attribute__((ext_vector_type(8)));

// ---- workspace layout (bytes) ----
#define WS_TILE_E 256                                   // int[MT_MAX]
#define WS_LOGITS 4096                                  // float[2048*16]
#define WS_SLOT_TOK (WS_LOGITS + T_TOK * NE * 4)        // int[SLOT_CAP]
#define WS_SLOT_W (WS_SLOT_TOK + SLOT_CAP * 4)          // float[SLOT_CAP]
#define WS_H1 (WS_SLOT_W + SLOT_CAP * 4)                // bf16[SLOT_CAP][ID]
#define WS_XB (WS_H1 + (size_t)SLOT_CAP * ID * 2)       // bf16[T][H]
#define WS_W2B (WS_XB + (size_t)T_TOK * HD * 2)         // bf16 E*H*I
#define WS_SW2B (WS_W2B + (size_t)NE * HD * ID * 2)     // bf16 H*I
#define WS_NEED (WS_SW2B + (size_t)ID * HD * 2)

__device__ __forceinline__ f32x4 mfma16(bf16x8 a, bf16x8 b, f32x4 c) {
  return __builtin_amdgcn_mfma_f32_16x16x32_bf16(a, b, c, 0, 0, 0);
}

__device__ __forceinline__ bf16x8 pack8(float4 a, float4 b) {
  bf16x8 o;
  o[0] = (__bf16)a.x; o[1] = (__bf16)a.y; o[2] = (__bf16)a.z; o[3] = (__bf16)a.w;
  o[4] = (__bf16)b.x; o[5] = (__bf16)b.y; o[6] = (__bf16)b.z; o[7] = (__bf16)b.w;
  return o;
}

// async global(16B/lane) -> LDS, linear dest (m97 pattern)
__device__ __forceinline__ void gload16(const __bf16* g, __bf16* l) {
  __builtin_amdgcn_global_load_lds(
      (const __attribute__((address_space(1))) uint32_t*)g,
      (__attribute__((address_space(3))) uint32_t*)l, 16, 0, 0);
}

// -------- fused_pre: router logits (512 blocks) + cvt of {w2, sw2, x} ------
#define W2G ((size_t)NE * HD * ID / 8)   // 2,097,152 groups of 8 floats
#define SWG ((size_t)ID * HD / 8)        // 131,072
#define XG ((size_t)T_TOK * HD / 8)      // 262,144
#define CVT_TOT (W2G + SWG + XG)
#define CVTB 1536
#define LOGITS_BLOCKS (T_TOK / 4)

__global__ __launch_bounds__(256) void fused_pre(
    const float* __restrict__ w2, const float* __restrict__ sw2,
    const float* __restrict__ x, __bf16* __restrict__ w2b,
    __bf16* __restrict__ sw2b, __bf16* __restrict__ xb,
    const float* __restrict__ gw, float* __restrict__ logits) {
  int tid = threadIdx.x;
  if ((int)blockIdx.x < LOGITS_BLOCKS) {
    // router logits: 4 waves/block, 1 token/wave, lane=(expert, quarter)
    int wv = tid >> 6;
    int lane = tid & 63;
    int tok = blockIdx.x * 4 + wv;
    int e = lane >> 2;
    int q = lane & 3;
    const float4* xr = (const float4*)(x + (size_t)tok * HD) + q * 64;
    const float4* wr = (const float4*)(gw + (size_t)e * HD) + q * 64;
    float s0 = 0.f, s1 = 0.f;
#pragma unroll 8
    for (int i = 0; i < 64; i += 2) {
      float4 a0 = xr[i], w0 = wr[i];
      float4 a1 = xr[i + 1], w1v = wr[i + 1];
      s0 += a0.x * w0.x + a0.y * w0.y + a0.z * w0.z + a0.w * w0.w;
      s1 += a1.x * w1v.x + a1.y * w1v.y + a1.z * w1v.z + a1.w * w1v.w;
    }
    float s = s0 + s1;
    s += __shfl_xor(s, 1);
    s += __shfl_xor(s, 2);
    if (q == 0) logits[(size_t)tok * NE + e] = s;
    return;
  }
  // grid-stride cvt: 32B read -> 16B bf16 write per lane per iter
  size_t b = blockIdx.x - LOGITS_BLOCKS;
  const size_t stride = (size_t)CVTB * 256;
  for (size_t i = b * 256 + tid; i < CVT_TOT; i += stride) {
    const float* src;
    __bf16* dst;
    size_t off;
    if (i < W2G) { src = w2; dst = w2b; off = i; }
    else if (i < W2G + SWG) { src = sw2; dst = sw2b; off = i - W2G; }
    else { src = x; dst = xb; off = i - W2G - SWG; }
    const float4* p = (const float4*)src + 2 * off;
    float4 a = p[0], c = p[1];
    *(bf16x8*)(dst + 8 * off) = pack8(a, c);
  }
}

// ------- router_finish: top-4 + softmax + scan + scatter (one block) -------
__global__ __launch_bounds__(256) void router_finish(
    const float* __restrict__ logits, const float* __restrict__ bias,
    int* __restrict__ tile_e, int* __restrict__ slot_tok,
    float* __restrict__ slot_w) {
  __shared__ int hist[NE];
  __shared__ int soff[NE + 1];
  __shared__ int fillp[NE];
  __shared__ unsigned lsel[T_TOK];
  __shared__ float4 lw4[T_TOK];

  int tid = threadIdx.x;
  if (tid < NE) { hist[tid] = 0; fillp[tid] = 0; }
  __syncthreads();

  float bb[NE];
#pragma unroll
  for (int e = 0; e < NE; ++e) bb[e] = bias[e];

  for (int j = 0; j < T_TOK / 256; ++j) {
    int t = tid + 256 * j;
    float lg[NE];
    const float4* lp = (const float4*)(logits + (size_t)t * NE);
#pragma unroll
    for (int q = 0; q < 4; ++q) {
      float4 v = lp[q];
      lg[4 * q] = v.x; lg[4 * q + 1] = v.y; lg[4 * q + 2] = v.z; lg[4 * q + 3] = v.w;
    }
    float b[NE];
#pragma unroll
    for (int e = 0; e < NE; ++e) b[e] = lg[e] + bb[e];

    int selk[TOPK];
    float raw[TOPK];
    unsigned used = 0;
#pragma unroll
    for (int k = 0; k < TOPK; ++k) {
      float best = -3.4e38f;
      int bi = 0;
#pragma unroll
      for (int e = 0; e < NE; ++e) {
        if (!((used >> e) & 1) && b[e] > best) { best = b[e]; bi = e; }
      }
      used |= (1u << bi);
      selk[k] = bi;
      raw[k] = lg[bi];
    }
    float m = raw[0];
#pragma unroll
    for (int k = 1; k < TOPK; ++k) m = fmaxf(m, raw[k]);
    float s = 0.f;
    float w[TOPK];
#pragma unroll
    for (int k = 0; k < TOPK; ++k) { w[k] = __expf(raw[k] - m); s += w[k]; }
    float inv = 1.f / s;
    lsel[t] = (unsigned)selk[0] | ((unsigned)selk[1] << 8) |
              ((unsigned)selk[2] << 16) | ((unsigned)selk[3] << 24);
    lw4[t] = make_float4(w[0] * inv, w[1] * inv, w[2] * inv, w[3] * inv);
#pragma unroll
    for (int k = 0; k < TOPK; ++k) atomicAdd(&hist[selk[k]], 1);
  }
  __syncthreads();

  if (tid == 0) {
    int o = 0;
    for (int e = 0; e < NE; ++e) { soff[e] = o; o += (hist[e] + BM - 1) & ~(BM - 1); }
    soff[NE] = o;
  }
  __syncthreads();
  int shared_base = soff[NE];
  int total = shared_base + T_TOK;
  for (int tt = tid; tt < MT_MAX; tt += 256) {
    int base = tt * BM;
    int ee = -1;
    if (base < shared_base) {
      ee = 0;
#pragma unroll
      for (int q = 1; q < NE; ++q) if (base >= soff[q]) ee = q;
    } else if (base < total) {
      ee = NE;
    }
    tile_e[tt] = ee;
  }

  for (int j = 0; j < T_TOK / 256; ++j) {
    int t = tid + 256 * j;
    unsigned ps = lsel[t];
    float4 wv = lw4[t];
    int e0 = ps & 255, e1 = (ps >> 8) & 255, e2 = (ps >> 16) & 255, e3 = ps >> 24;
    int p0 = atomicAdd(&fillp[e0], 1);
    slot_tok[soff[e0] + p0] = t; slot_w[soff[e0] + p0] = wv.x;
    int p1 = atomicAdd(&fillp[e1], 1);
    slot_tok[soff[e1] + p1] = t; slot_w[soff[e1] + p1] = wv.y;
    int p2 = atomicAdd(&fillp[e2], 1);
    slot_tok[soff[e2] + p2] = t; slot_w[soff[e2] + p2] = wv.z;
    int p3 = atomicAdd(&fillp[e3], 1);
    slot_tok[soff[e3] + p3] = t; slot_w[soff[e3] + p3] = wv.w;
  }

  for (int s = tid; s < shared_base; s += 256) {
    int e = 0;
#pragma unroll
    for (int q = 1; q < NE; ++q) if (s >= soff[q]) e = q;
    if (s >= soff[e] + hist[e]) { slot_tok[s] = -1; slot_w[s] = 0.f; }
  }
  for (int s = shared_base + tid; s < total; s += 256) {
    slot_tok[s] = s - shared_base;
    slot_w[s] = 1.0f;
  }
}

// ============ pass 1: h1 = silu(x w1^T) * (x w3^T), fp32 weights ============
// A (bf16 xb): global_load_lds direct.  B (fp32 w1/w3): reg-staged cvt —
// issue 8 float4 loads + 2 A-gloads for k+1 BEFORE ds_read+MFMA(k); vmcnt(0)
// only after MFMA (loads fly under compute; B panels L2-hit after first
// m-tile since XCD = blockIdx.x = n-stripe).  One barrier per K-step.
// (256,2): acc 128 + stage 32 + frags 24 regs; 3/EU would spill (round-5).
__global__ __launch_bounds__(256, 2) void pass1_bf16(
    const __bf16* __restrict__ xb, const int* __restrict__ slot_tok,
    const int* __restrict__ tile_e, const float* __restrict__ w1,
    const float* __restrict__ w3, const float* __restrict__ sw1,
    const float* __restrict__ sw3, __bf16* __restrict__ h1) {
  int mt = blockIdx.y;
  int e = tile_e[mt];
  if (e < 0) return;
  int n0 = blockIdx.x * BN;
  int m0 = mt * BM;

  const float* wg = (e == NE) ? sw1 : w1 + (size_t)e * ID * HD;
  const float* wu = (e == NE) ? sw3 : w3 + (size_t)e * ID * HD;

  __shared__ __align__(16) __bf16 As[2][BM * BK];
  __shared__ __align__(16) __bf16 Bg[2][BN * BK];
  __shared__ __align__(16) __bf16 Bu[2][BN * BK];

  int tid = threadIdx.x;
  // A staging (swizzled global source, linear LDS dest)
  int r0 = tid >> 2, r1 = r0 + 64;
  int c8 = ((tid & 3) ^ ((r0 >> 1) & 3)) * 8;
  int tok0 = slot_tok[m0 + r0]; if (tok0 < 0) tok0 = 0;
  int tok1 = slot_tok[m0 + r1]; if (tok1 < 0) tok1 = 0;
  const __bf16* gA0 = xb + (size_t)tok0 * HD + c8;
  const __bf16* gA1 = xb + (size_t)tok1 * HD + c8;

  // B staging: thread covers row=tid>>1, 16 cols at half*16
  int brow = tid >> 1;
  int bhalf = tid & 1;
  int bsw = (brow >> 1) & 3;
  const float* gW = wg + (size_t)(n0 + brow) * HD + bhalf * 16;
  const float* gU = wu + (size_t)(n0 + brow) * HD + bhalf * 16;
  int slot0 = (((bhalf * 2) ^ bsw) * 8) + brow * BK;      // bf16 offsets
  int slot1 = (((bhalf * 2 + 1) ^ bsw) * 8) + brow * BK;

  int wave = tid >> 6, lane = tid & 63;
  int wm = (wave >> 1) * 64, wn = (wave & 1) * 64;
  int l16 = lane & 15, kch = lane >> 4;
  int kk8 = (kch ^ ((l16 >> 1) & 3)) * 8;

  f32x4 accg[4][4] = {};
  f32x4 accu[4][4] = {};

  // ---- prologue: stage tile 0 ----
  {
    float4 g0 = *(const float4*)(gW);
    float4 g1 = *(const float4*)(gW + 4);
    float4 g2 = *(const float4*)(gW + 8);
    float4 g3 = *(const float4*)(gW + 12);
    float4 v0 = *(const float4*)(gU);
    float4 v1 = *(const float4*)(gU + 4);
    float4 v2 = *(const float4*)(gU + 8);
    float4 v3 = *(const float4*)(gU + 12);
    gload16(gA0, &As[0][(size_t)tid * 8]);
    gload16(gA1, &As[0][(size_t)(tid + 256) * 8]);
    asm volatile("s_waitcnt vmcnt(0)" ::: "memory");
    *(bf16x8*)(&Bg[0][slot0]) = pack8(g0, g1);
    *(bf16x8*)(&Bg[0][slot1]) = pack8(g2, g3);
    *(bf16x8*)(&Bu[0][slot0]) = pack8(v0, v1);
    *(bf16x8*)(&Bu[0][slot1]) = pack8(v2, v3);
    asm volatile("s_waitcnt lgkmcnt(0)" ::: "memory");
    __builtin_amdgcn_s_barrier();
  }

#pragma unroll 1
  for (int k = 0; k < NK1; ++k) {
    int cur = k & 1;
    bool pf = (k + 1 < NK1);
    float4 g0, g1, g2, g3, v0, v1, v2, v3;
    if (pf) {
      const float* pW = gW + (k + 1) * BK;
      const float* pU = gU + (k + 1) * BK;
      g0 = *(const float4*)(pW);
      g1 = *(const float4*)(pW + 4);
      g2 = *(const float4*)(pW + 8);
      g3 = *(const float4*)(pW + 12);
      v0 = *(const float4*)(pU);
      v1 = *(const float4*)(pU + 4);
      v2 = *(const float4*)(pU + 8);
      v3 = *(const float4*)(pU + 12);
      gload16(gA0 + (k + 1) * BK, &As[cur ^ 1][(size_t)tid * 8]);
      gload16(gA1 + (k + 1) * BK, &As[cur ^ 1][(size_t)(tid + 256) * 8]);
    }
    bf16x8 af[4], gf[4], uf[4];
#pragma unroll
    for (int i = 0; i < 4; ++i) {
      af[i] = *(const bf16x8*)(&As[cur][(wm + i * 16 + l16) * BK + kk8]);
      gf[i] = *(const bf16x8*)(&Bg[cur][(wn + i * 16 + l16) * BK + kk8]);
      uf[i] = *(const bf16x8*)(&Bu[cur][(wn + i * 16 + l16) * BK + kk8]);
    }
    asm volatile("s_waitcnt lgkmcnt(0)" ::: "memory");
    __builtin_amdgcn_sched_barrier(0);  // rule #18
#pragma unroll
    for (int mi = 0; mi < 4; ++mi)
#pragma unroll
      for (int ni = 0; ni < 4; ++ni) {
        accg[mi][ni] = mfma16(af[mi], gf[ni], accg[mi][ni]);
        accu[mi][ni] = mfma16(af[mi], uf[ni], accu[mi][ni]);
      }
    if (pf) {
      asm volatile("s_waitcnt vmcnt(0)" ::: "memory");  // regs + A DMA landed
      *(bf16x8*)(&Bg[cur ^ 1][slot0]) = pack8(g0, g1);
      *(bf16x8*)(&Bg[cur ^ 1][slot1]) = pack8(g2, g3);
      *(bf16x8*)(&Bu[cur ^ 1][slot0]) = pack8(v0, v1);
      *(bf16x8*)(&Bu[cur ^ 1][slot1]) = pack8(v2, v3);
      asm volatile("s_waitcnt lgkmcnt(0)" ::: "memory");
      __builtin_amdgcn_s_barrier();
    }
  }

#pragma unroll
  for (int mi = 0; mi < 4; ++mi) {
#pragma unroll
    for (int ni = 0; ni < 4; ++ni) {
#pragma unroll
      for (int j = 0; j < 4; ++j) {
        int row = m0 + wm + mi * 16 + kch * 4 + j;
        int col = n0 + wn + ni * 16 + l16;
        float g = accg[mi][ni][j];
        float u = accu[mi][ni][j];
        float hv = (g / (1.f + __expf(-g))) * u;
        h1[(size_t)row * ID + col] = (__bf16)hv;
      }
    }
  }
}

// ====== pass 2: out += g * (h1 w2^T) — bf16 gload_lds, counted vmcnt =======
__global__ __launch_bounds__(256, 3) void pass2_bf16(
    const __bf16* __restrict__ h1, const int* __restrict__ slot_tok,
    const float* __restrict__ slot_w, const int* __restrict__ tile_e,
    const __bf16* __restrict__ w2b, const __bf16* __restrict__ sw2b,
    float* __restrict__ out) {
  int mt = blockIdx.y;
  int e = tile_e[mt];
  if (e < 0) return;
  int n0 = blockIdx.x * BN;
  int m0 = mt * BM;

  const __bf16* wd = (e == NE) ? sw2b : w2b + (size_t)e * HD * ID;

  __shared__ __align__(16) __bf16 As[2][BM * BK];
  __shared__ __align__(16) __bf16 Bs[2][BN * BK];

  int tid = threadIdx.x;
  int r0 = tid >> 2, r1 = r0 + 64;
  int c8 = ((tid & 3) ^ ((r0 >> 1) & 3)) * 8;
  const __bf16* gA0 = h1 + (size_t)(m0 + r0) * ID + c8;
  const __bf16* gA1 = h1 + (size_t)(m0 + r1) * ID + c8;
  const __bf16* gB0 = wd + (size_t)(n0 + r0) * ID + c8;
  const __bf16* gB1 = wd + (size_t)(n0 + r1) * ID + c8;

  int wave = tid >> 6, lane = tid & 63;
  int wm = (wave >> 1) * 64, wn = (wave & 1) * 64;
  int l16 = lane & 15, kch = lane >> 4;
  int kk8 = (kch ^ ((l16 >> 1) & 3)) * 8;

  f32x4 acc[4][4] = {};

  auto stage = [&](int B, int k0) {
    gload16(gA0 + k0, &As[B][(size_t)tid * 8]);
    gload16(gA1 + k0, &As[B][(size_t)(tid + 256) * 8]);
    gload16(gB0 + k0, &Bs[B][(size_t)tid * 8]);
    gload16(gB1 + k0, &Bs[B][(size_t)(tid + 256) * 8]);
  };
  auto body = [&](int B) {
    bf16x8 af[4], bf[4];
#pragma unroll
    for (int i = 0; i < 4; ++i) {
      af[i] = *(const bf16x8*)(&As[B][(wm + i * 16 + l16) * BK + kk8]);
      bf[i] = *(const bf16x8*)(&Bs[B][(wn + i * 16 + l16) * BK + kk8]);
    }
    asm volatile("s_waitcnt lgkmcnt(0)" ::: "memory");
    __builtin_amdgcn_s_barrier();
    __builtin_amdgcn_sched_barrier(0);
#pragma unroll
    for (int mi = 0; mi < 4; ++mi)
#pragma unroll
      for (int ni = 0; ni < 4; ++ni)
        acc[mi][ni] = mfma16(af[mi], bf[ni], acc[mi][ni]);
  };

  stage(0, 0);
#pragma unroll 1
  for (int k = 0; k < ID / BK - 1; ++k) {
    int cur = k & 1;
    stage(cur ^ 1, (k + 1) * BK);
    asm volatile("s_waitcnt vmcnt(4)" ::: "memory");
    __builtin_amdgcn_s_barrier();
    __builtin_amdgcn_sched_barrier(0);
    body(cur);
  }
  asm volatile("s_waitcnt vmcnt(0)" ::: "memory");
  __builtin_amdgcn_s_barrier();
  __builtin_amdgcn_sched_barrier(0);
  body((ID / BK - 1) & 1);

#pragma unroll
  for (int mi = 0; mi < 4; ++mi) {
#pragma unroll
    for (int j = 0; j < 4; ++j) {
      int row = m0 + wm + mi * 16 + kch * 4 + j;
      int token = slot_tok[row];
      if (token < 0) continue;
      float wgt = slot_w[row];
#pragma unroll
      for (int ni = 0; ni < 4; ++ni) {
        int col = n0 + wn + ni * 16 + l16;
        atomicAdd(out + (size_t)token * HD + col, wgt * acc[mi][ni][j]);
      }
    }
  }
}

// ---------------- launcher ----------------
extern "C" void kernel_launch(void* const* d_in, const int* in_sizes, int n_in,
                              void* d_out, int out_size, void* d_ws, size_t ws_size,
                              hipStream_t stream) {
  const float* x = (const float*)d_in[0];
  const float* gate_w = (const float*)d_in[1];
  const float* ebias = (const float*)d_in[2];
  const float* w1 = (const float*)d_in[3];
  const float* w2 = (const float*)d_in[4];
  const float* w3 = (const float*)d_in[5];
  const float* sw1 = (const float*)d_in[6];
  const float* sw2 = (const float*)d_in[7];
  const float* sw3 = (const float*)d_in[8];
  float* out = (float*)d_out;

  char* ws = (char*)d_ws;
  int* tile_e = (int*)(ws + WS_TILE_E);
  float* logits = (float*)(ws + WS_LOGITS);
  int* slot_tok = (int*)(ws + WS_SLOT_TOK);
  float* slot_w = (float*)(ws + WS_SLOT_W);
  __bf16* h1 = (__bf16*)(ws + WS_H1);
  __bf16* xb = (__bf16*)(ws + WS_XB);
  __bf16* w2b = (__bf16*)(ws + WS_W2B);
  __bf16* sw2b = (__bf16*)(ws + WS_SW2B);

  hipMemsetAsync(d_out, 0, (size_t)T_TOK * HD * sizeof(float), stream);

  fused_pre<<<LOGITS_BLOCKS + CVTB, 256, 0, stream>>>(w2, sw2, x, w2b, sw2b, xb,
                                                      gate_w, logits);
  router_finish<<<1, 256, 0, stream>>>(logits, ebias, tile_e, slot_tok, slot_w);

  pass1_bf16<<<dim3(ID / BN, MT_MAX), 256, 0, stream>>>(
      xb, slot_tok, tile_e, w1, w3, sw1, sw3, h1);
  pass2_bf16<<<dim3(HD / BN, MT_MAX), 256, 0, stream>>>(
      h1, slot_tok, slot_w, tile_e, w2b, sw2b, out);
}

// Round 9
// 265.295 us; speedup vs baseline: 1.0843x; 1.0843x over previous
//
#include <hip/hip_runtime.h>
#include <cstddef>
#include <cstdint>

#define T_TOK 2048
#define HD 1024
#define ID 1024
#define NE 16
#define TOPK 4
#define BM 128
#define BN 128
#define BK 32
#define MT_MAX 96
#define SLOT_CAP (MT_MAX * BM)

typedef float f32x4 __attribute__((ext_vector_type(4)));
typedef __bf16 bf16x8 __attribute__((ext_vector_type(8)));

// ---- workspace layout (bytes) ----
#define WS_TILE_E 256                                   // int[MT_MAX]
#define WS_LOGITS 4096                                  // float[2048*16]
#define WS_SLOT_TOK (WS_LOGITS + T_TOK * NE * 4)        // int[SLOT_CAP]
#define WS_SLOT_W (WS_SLOT_TOK + SLOT_CAP * 4)          // float[SLOT_CAP]
#define WS_H1 (WS_SLOT_W + SLOT_CAP * 4)                // bf16[SLOT_CAP][ID]
#define WS_XB (WS_H1 + (size_t)SLOT_CAP * ID * 2)       // bf16[T][H]
#define WS_W1B (WS_XB + (size_t)T_TOK * HD * 2)         // bf16 E*I*H
#define WS_W2B (WS_W1B + (size_t)NE * ID * HD * 2)
#define WS_W3B (WS_W2B + (size_t)NE * HD * ID * 2)
#define WS_SW1B (WS_W3B + (size_t)NE * ID * HD * 2)
#define WS_SW2B (WS_SW1B + (size_t)ID * HD * 2)
#define WS_SW3B (WS_SW2B + (size_t)HD * ID * 2)
#define WS_NEED (WS_SW3B + (size_t)ID * HD * 2)

__device__ __forceinline__ f32x4 mfma16(bf16x8 a, bf16x8 b, f32x4 c) {
  return __builtin_amdgcn_mfma_f32_16x16x32_bf16(a, b, c, 0, 0, 0);
}

__device__ __forceinline__ bf16x8 pack8(f32x4 a, f32x4 b) {
  bf16x8 o;
  o[0] = (__bf16)a[0]; o[1] = (__bf16)a[1]; o[2] = (__bf16)a[2]; o[3] = (__bf16)a[3];
  o[4] = (__bf16)b[0]; o[5] = (__bf16)b[1]; o[6] = (__bf16)b[2]; o[7] = (__bf16)b[3];
  return o;
}

// async global(16B/lane) -> LDS, linear dest (m97 pattern)
__device__ __forceinline__ void gload16(const __bf16* g, __bf16* l) {
  __builtin_amdgcn_global_load_lds(
      (const __attribute__((address_space(1))) uint32_t*)g,
      (__attribute__((address_space(3))) uint32_t*)l, 16, 0, 0);
}

// ---- fused_pre: router logits (512 blocks) + unrolled cvt (2048 blocks) ----
// cvt works in units of 8 float4 (32 floats): 8 INDEPENDENT 16B loads per
// iter per thread (MLP=8; round-7's MLP=1 chain was the 2.46 TB/s limiter).
#define W8 ((size_t)1 << 19)   // 8-float4 units per big weight tensor
#define S8 ((size_t)1 << 15)   // per shared weight tensor
#define X8 ((size_t)1 << 16)   // x
#define CVT8_TOTAL (3 * W8 + 3 * S8 + X8)
#define CVT_GRID 2048
#define LOGITS_BLOCKS (T_TOK / 4)

__global__ __launch_bounds__(256) void fused_pre(
    const float* __restrict__ w1, const float* __restrict__ w2,
    const float* __restrict__ w3, const float* __restrict__ sw1,
    const float* __restrict__ sw2, const float* __restrict__ sw3,
    const float* __restrict__ x, __bf16* __restrict__ w1b,
    __bf16* __restrict__ w2b, __bf16* __restrict__ w3b,
    __bf16* __restrict__ sw1b, __bf16* __restrict__ sw2b,
    __bf16* __restrict__ sw3b, __bf16* __restrict__ xb,
    const float* __restrict__ gw, float* __restrict__ logits) {
  int tid = threadIdx.x;
  if ((int)blockIdx.x < LOGITS_BLOCKS) {
    int wv = tid >> 6;
    int lane = tid & 63;
    int tok = blockIdx.x * 4 + wv;
    int e = lane >> 2;
    int q = lane & 3;
    const float4* xr = (const float4*)(x + (size_t)tok * HD) + q * 64;
    const float4* wr = (const float4*)(gw + (size_t)e * HD) + q * 64;
    float s0 = 0.f, s1 = 0.f;
#pragma unroll 8
    for (int i = 0; i < 64; i += 2) {
      float4 a0 = xr[i], w0 = wr[i];
      float4 a1 = xr[i + 1], w1v = wr[i + 1];
      s0 += a0.x * w0.x + a0.y * w0.y + a0.z * w0.z + a0.w * w0.w;
      s1 += a1.x * w1v.x + a1.y * w1v.y + a1.z * w1v.z + a1.w * w1v.w;
    }
    float s = s0 + s1;
    s += __shfl_xor(s, 1);
    s += __shfl_xor(s, 2);
    if (q == 0) logits[(size_t)tok * NE + e] = s;
    return;
  }
  size_t b = blockIdx.x - LOGITS_BLOCKS;
  const size_t stride = (size_t)CVT_GRID * 256;
  for (size_t u = b * 256 + tid; u < CVT8_TOTAL; u += stride) {
    const float* src;
    __bf16* dst;
    size_t off8;
    if (u < 3 * W8) {
      size_t t = u >> 19;
      off8 = u & (W8 - 1);
      src = (t == 0) ? w1 : (t == 1) ? w2 : w3;
      dst = (t == 0) ? w1b : (t == 1) ? w2b : w3b;
    } else {
      size_t j = u - 3 * W8;
      if (j < 3 * S8) {
        size_t t = j >> 15;
        off8 = j & (S8 - 1);
        src = (t == 0) ? sw1 : (t == 1) ? sw2 : sw3;
        dst = (t == 0) ? sw1b : (t == 1) ? sw2b : sw3b;
      } else {
        off8 = j - 3 * S8;
        src = x;
        dst = xb;
      }
    }
    const f32x4* p = (const f32x4*)src + 8 * off8;
    f32x4 v0 = p[0], v1 = p[1], v2 = p[2], v3 = p[3];
    f32x4 v4 = p[4], v5 = p[5], v6 = p[6], v7 = p[7];
    bf16x8* q = (bf16x8*)(dst + 32 * off8);
    q[0] = pack8(v0, v1);
    q[1] = pack8(v2, v3);
    q[2] = pack8(v4, v5);
    q[3] = pack8(v6, v7);
  }
}

// ------- router_finish: top-4 + softmax + scan + scatter (one block) -------
__global__ __launch_bounds__(256) void router_finish(
    const float* __restrict__ logits, const float* __restrict__ bias,
    int* __restrict__ tile_e, int* __restrict__ slot_tok,
    float* __restrict__ slot_w) {
  __shared__ int hist[NE];
  __shared__ int soff[NE + 1];
  __shared__ int fillp[NE];
  __shared__ unsigned lsel[T_TOK];
  __shared__ float4 lw4[T_TOK];

  int tid = threadIdx.x;
  if (tid < NE) { hist[tid] = 0; fillp[tid] = 0; }
  __syncthreads();

  float bb[NE];
#pragma unroll
  for (int e = 0; e < NE; ++e) bb[e] = bias[e];

  for (int j = 0; j < T_TOK / 256; ++j) {
    int t = tid + 256 * j;
    float lg[NE];
    const float4* lp = (const float4*)(logits + (size_t)t * NE);
#pragma unroll
    for (int q = 0; q < 4; ++q) {
      float4 v = lp[q];
      lg[4 * q] = v.x; lg[4 * q + 1] = v.y; lg[4 * q + 2] = v.z; lg[4 * q + 3] = v.w;
    }
    float b[NE];
#pragma unroll
    for (int e = 0; e < NE; ++e) b[e] = lg[e] + bb[e];

    int selk[TOPK];
    float raw[TOPK];
    unsigned used = 0;
#pragma unroll
    for (int k = 0; k < TOPK; ++k) {
      float best = -3.4e38f;
      int bi = 0;
#pragma unroll
      for (int e = 0; e < NE; ++e) {
        if (!((used >> e) & 1) && b[e] > best) { best = b[e]; bi = e; }
      }
      used |= (1u << bi);
      selk[k] = bi;
      raw[k] = lg[bi];
    }
    float m = raw[0];
#pragma unroll
    for (int k = 1; k < TOPK; ++k) m = fmaxf(m, raw[k]);
    float s = 0.f;
    float w[TOPK];
#pragma unroll
    for (int k = 0; k < TOPK; ++k) { w[k] = __expf(raw[k] - m); s += w[k]; }
    float inv = 1.f / s;
    lsel[t] = (unsigned)selk[0] | ((unsigned)selk[1] << 8) |
              ((unsigned)selk[2] << 16) | ((unsigned)selk[3] << 24);
    lw4[t] = make_float4(w[0] * inv, w[1] * inv, w[2] * inv, w[3] * inv);
#pragma unroll
    for (int k = 0; k < TOPK; ++k) atomicAdd(&hist[selk[k]], 1);
  }
  __syncthreads();

  if (tid == 0) {
    int o = 0;
    for (int e = 0; e < NE; ++e) { soff[e] = o; o += (hist[e] + BM - 1) & ~(BM - 1); }
    soff[NE] = o;
  }
  __syncthreads();
  int shared_base = soff[NE];
  int total = shared_base + T_TOK;
  for (int tt = tid; tt < MT_MAX; tt += 256) {
    int base = tt * BM;
    int ee = -1;
    if (base < shared_base) {
      ee = 0;
#pragma unroll
      for (int q = 1; q < NE; ++q) if (base >= soff[q]) ee = q;
    } else if (base < total) {
      ee = NE;
    }
    tile_e[tt] = ee;
  }

  for (int j = 0; j < T_TOK / 256; ++j) {
    int t = tid + 256 * j;
    unsigned ps = lsel[t];
    float4 wv = lw4[t];
    int e0 = ps & 255, e1 = (ps >> 8) & 255, e2 = (ps >> 16) & 255, e3 = ps >> 24;
    int p0 = atomicAdd(&fillp[e0], 1);
    slot_tok[soff[e0] + p0] = t; slot_w[soff[e0] + p0] = wv.x;
    int p1 = atomicAdd(&fillp[e1], 1);
    slot_tok[soff[e1] + p1] = t; slot_w[soff[e1] + p1] = wv.y;
    int p2 = atomicAdd(&fillp[e2], 1);
    slot_tok[soff[e2] + p2] = t; slot_w[soff[e2] + p2] = wv.z;
    int p3 = atomicAdd(&fillp[e3], 1);
    slot_tok[soff[e3] + p3] = t; slot_w[soff[e3] + p3] = wv.w;
  }

  for (int s = tid; s < shared_base; s += 256) {
    int e = 0;
#pragma unroll
    for (int q = 1; q < NE; ++q) if (s >= soff[q]) e = q;
    if (s >= soff[e] + hist[e]) { slot_tok[s] = -1; slot_w[s] = 0.f; }
  }
  for (int s = shared_base + tid; s < total; s += 256) {
    slot_tok[s] = s - shared_base;
    slot_w[s] = 1.0f;
  }
}

// ===== bf16 GEMMs: dbuf + COUNTED vmcnt pipeline (T3/T4) + XOR swizzle ======
// (proven round-7 structure; raw s_barrier avoids the vmcnt(0) drain)

// pass 1: h1 = silu(x w1^T) * (x w3^T).  (256,2): accs=128 regs, 3/EU spills.
__global__ __launch_bounds__(256, 2) void pass1_bf16(
    const __bf16* __restrict__ xb, const int* __restrict__ slot_tok,
    const int* __restrict__ tile_e, const __bf16* __restrict__ w1b,
    const __bf16* __restrict__ w3b, const __bf16* __restrict__ sw1b,
    const __bf16* __restrict__ sw3b, __bf16* __restrict__ h1) {
  int mt = blockIdx.y;
  int e = tile_e[mt];
  if (e < 0) return;
  int n0 = blockIdx.x * BN;
  int m0 = mt * BM;

  const __bf16* wg = (e == NE) ? sw1b : w1b + (size_t)e * ID * HD;
  const __bf16* wu = (e == NE) ? sw3b : w3b + (size_t)e * ID * HD;

  __shared__ __align__(16) __bf16 As[2][BM * BK];
  __shared__ __align__(16) __bf16 Bg[2][BN * BK];
  __shared__ __align__(16) __bf16 Bu[2][BN * BK];

  int tid = threadIdx.x;
  int r0 = tid >> 2, r1 = r0 + 64;
  int c8 = ((tid & 3) ^ ((r0 >> 1) & 3)) * 8;  // pre-swizzled global chunk
  int tok0 = slot_tok[m0 + r0]; if (tok0 < 0) tok0 = 0;
  int tok1 = slot_tok[m0 + r1]; if (tok1 < 0) tok1 = 0;
  const __bf16* gA0 = xb + (size_t)tok0 * HD + c8;
  const __bf16* gA1 = xb + (size_t)tok1 * HD + c8;
  const __bf16* gG0 = wg + (size_t)(n0 + r0) * HD + c8;
  const __bf16* gG1 = wg + (size_t)(n0 + r1) * HD + c8;
  const __bf16* gU0 = wu + (size_t)(n0 + r0) * HD + c8;
  const __bf16* gU1 = wu + (size_t)(n0 + r1) * HD + c8;

  int wave = tid >> 6, lane = tid & 63;
  int wm = (wave >> 1) * 64, wn = (wave & 1) * 64;
  int l16 = lane & 15, kch = lane >> 4;
  int kk8 = (kch ^ ((l16 >> 1) & 3)) * 8;  // swizzled read chunk

  f32x4 accg[4][4] = {};
  f32x4 accu[4][4] = {};

  auto stage = [&](int B, int k0) {
    gload16(gA0 + k0, &As[B][(size_t)tid * 8]);
    gload16(gA1 + k0, &As[B][(size_t)(tid + 256) * 8]);
    gload16(gG0 + k0, &Bg[B][(size_t)tid * 8]);
    gload16(gG1 + k0, &Bg[B][(size_t)(tid + 256) * 8]);
    gload16(gU0 + k0, &Bu[B][(size_t)tid * 8]);
    gload16(gU1 + k0, &Bu[B][(size_t)(tid + 256) * 8]);
  };
  auto body = [&](int B) {
    bf16x8 af[4], gf[4], uf[4];
#pragma unroll
    for (int i = 0; i < 4; ++i) {
      af[i] = *(const bf16x8*)(&As[B][(wm + i * 16 + l16) * BK + kk8]);
      gf[i] = *(const bf16x8*)(&Bg[B][(wn + i * 16 + l16) * BK + kk8]);
      uf[i] = *(const bf16x8*)(&Bu[B][(wn + i * 16 + l16) * BK + kk8]);
    }
    asm volatile("s_waitcnt lgkmcnt(0)" ::: "memory");
    __builtin_amdgcn_s_barrier();            // buffer free for next stage
    __builtin_amdgcn_sched_barrier(0);       // rule #18
#pragma unroll
    for (int mi = 0; mi < 4; ++mi)
#pragma unroll
      for (int ni = 0; ni < 4; ++ni) {
        accg[mi][ni] = mfma16(af[mi], gf[ni], accg[mi][ni]);
        accu[mi][ni] = mfma16(af[mi], uf[ni], accu[mi][ni]);
      }
  };

  stage(0, 0);
#pragma unroll 1
  for (int k = 0; k < HD / BK - 1; ++k) {
    int cur = k & 1;
    stage(cur ^ 1, (k + 1) * BK);            // 6 loads stay in flight
    asm volatile("s_waitcnt vmcnt(6)" ::: "memory");
    __builtin_amdgcn_s_barrier();
    __builtin_amdgcn_sched_barrier(0);
    body(cur);
  }
  asm volatile("s_waitcnt vmcnt(0)" ::: "memory");
  __builtin_amdgcn_s_barrier();
  __builtin_amdgcn_sched_barrier(0);
  body((HD / BK - 1) & 1);

#pragma unroll
  for (int mi = 0; mi < 4; ++mi) {
#pragma unroll
    for (int ni = 0; ni < 4; ++ni) {
#pragma unroll
      for (int j = 0; j < 4; ++j) {
        int row = m0 + wm + mi * 16 + kch * 4 + j;
        int col = n0 + wn + ni * 16 + l16;
        float g = accg[mi][ni][j];
        float u = accu[mi][ni][j];
        float hv = (g / (1.f + __expf(-g))) * u;
        h1[(size_t)row * ID + col] = (__bf16)hv;
      }
    }
  }
}

// pass 2: out += g * (h1 w2^T)
__global__ __launch_bounds__(256, 3) void pass2_bf16(
    const __bf16* __restrict__ h1, const int* __restrict__ slot_tok,
    const float* __restrict__ slot_w, const int* __restrict__ tile_e,
    const __bf16* __restrict__ w2b, const __bf16* __restrict__ sw2b,
    float* __restrict__ out) {
  int mt = blockIdx.y;
  int e = tile_e[mt];
  if (e < 0) return;
  int n0 = blockIdx.x * BN;
  int m0 = mt * BM;

  const __bf16* wd = (e == NE) ? sw2b : w2b + (size_t)e * HD * ID;

  __shared__ __align__(16) __bf16 As[2][BM * BK];
  __shared__ __align__(16) __bf16 Bs[2][BN * BK];

  int tid = threadIdx.x;
  int r0 = tid >> 2, r1 = r0 + 64;
  int c8 = ((tid & 3) ^ ((r0 >> 1) & 3)) * 8;
  const __bf16* gA0 = h1 + (size_t)(m0 + r0) * ID + c8;
  const __bf16* gA1 = h1 + (size_t)(m0 + r1) * ID + c8;
  const __bf16* gB0 = wd + (size_t)(n0 + r0) * ID + c8;
  const __bf16* gB1 = wd + (size_t)(n0 + r1) * ID + c8;

  int wave = tid >> 6, lane = tid & 63;
  int wm = (wave >> 1) * 64, wn = (wave & 1) * 64;
  int l16 = lane & 15, kch = lane >> 4;
  int kk8 = (kch ^ ((l16 >> 1) & 3)) * 8;

  f32x4 acc[4][4] = {};

  auto stage = [&](int B, int k0) {
    gload16(gA0 + k0, &As[B][(size_t)tid * 8]);
    gload16(gA1 + k0, &As[B][(size_t)(tid + 256) * 8]);
    gload16(gB0 + k0, &Bs[B][(size_t)tid * 8]);
    gload16(gB1 + k0, &Bs[B][(size_t)(tid + 256) * 8]);
  };
  auto body = [&](int B) {
    bf16x8 af[4], bf[4];
#pragma unroll
    for (int i = 0; i < 4; ++i) {
      af[i] = *(const bf16x8*)(&As[B][(wm + i * 16 + l16) * BK + kk8]);
      bf[i] = *(const bf16x8*)(&Bs[B][(wn + i * 16 + l16) * BK + kk8]);
    }
    asm volatile("s_waitcnt lgkmcnt(0)" ::: "memory");
    __builtin_amdgcn_s_barrier();
    __builtin_amdgcn_sched_barrier(0);
#pragma unroll
    for (int mi = 0; mi < 4; ++mi)
#pragma unroll
      for (int ni = 0; ni < 4; ++ni)
        acc[mi][ni] = mfma16(af[mi], bf[ni], acc[mi][ni]);
  };

  stage(0, 0);
#pragma unroll 1
  for (int k = 0; k < ID / BK - 1; ++k) {
    int cur = k & 1;
    stage(cur ^ 1, (k + 1) * BK);
    asm volatile("s_waitcnt vmcnt(4)" ::: "memory");
    __builtin_amdgcn_s_barrier();
    __builtin_amdgcn_sched_barrier(0);
    body(cur);
  }
  asm volatile("s_waitcnt vmcnt(0)" ::: "memory");
  __builtin_amdgcn_s_barrier();
  __builtin_amdgcn_sched_barrier(0);
  body((ID / BK - 1) & 1);

#pragma unroll
  for (int mi = 0; mi < 4; ++mi) {
#pragma unroll
    for (int j = 0; j < 4; ++j) {
      int row = m0 + wm + mi * 16 + kch * 4 + j;
      int token = slot_tok[row];
      if (token < 0) continue;
      float wgt = slot_w[row];
#pragma unroll
      for (int ni = 0; ni < 4; ++ni) {
        int col = n0 + wn + ni * 16 + l16;
        atomicAdd(out + (size_t)token * HD + col, wgt * acc[mi][ni][j]);
      }
    }
  }
}

// ---------------- launcher ----------------
extern "C" void kernel_launch(void* const* d_in, const int* in_sizes, int n_in,
                              void* d_out, int out_size, void* d_ws, size_t ws_size,
                              hipStream_t stream) {
  const float* x = (const float*)d_in[0];
  const float* gate_w = (const float*)d_in[1];
  const float* ebias = (const float*)d_in[2];
  const float* w1 = (const float*)d_in[3];
  const float* w2 = (const float*)d_in[4];
  const float* w3 = (const float*)d_in[5];
  const float* sw1 = (const float*)d_in[6];
  const float* sw2 = (const float*)d_in[7];
  const float* sw3 = (const float*)d_in[8];
  float* out = (float*)d_out;

  char* ws = (char*)d_ws;
  int* tile_e = (int*)(ws + WS_TILE_E);
  float* logits = (float*)(ws + WS_LOGITS);
  int* slot_tok = (int*)(ws + WS_SLOT_TOK);
  float* slot_w = (float*)(ws + WS_SLOT_W);
  __bf16* h1 = (__bf16*)(ws + WS_H1);
  __bf16* xb = (__bf16*)(ws + WS_XB);
  __bf16* w1b = (__bf16*)(ws + WS_W1B);
  __bf16* w2b = (__bf16*)(ws + WS_W2B);
  __bf16* w3b = (__bf16*)(ws + WS_W3B);
  __bf16* sw1b = (__bf16*)(ws + WS_SW1B);
  __bf16* sw2b = (__bf16*)(ws + WS_SW2B);
  __bf16* sw3b = (__bf16*)(ws + WS_SW3B);

  hipMemsetAsync(d_out, 0, (size_t)T_TOK * HD * sizeof(float), stream);

  fused_pre<<<LOGITS_BLOCKS + CVT_GRID, 256, 0, stream>>>(
      w1, w2, w3, sw1, sw2, sw3, x, w1b, w2b, w3b, sw1b, sw2b, sw3b, xb,
      gate_w, logits);
  router_finish<<<1, 256, 0, stream>>>(logits, ebias, tile_e, slot_tok, slot_w);

  pass1_bf16<<<dim3(ID / BN, MT_MAX), 256, 0, stream>>>(
      xb, slot_tok, tile_e, w1b, w3b, sw1b, sw3b, h1);
  pass2_bf16<<<dim3(HD / BN, MT_MAX), 256, 0, stream>>>(
      h1, slot_tok, slot_w, tile_e, w2b, sw2b, out);
}

// Round 10
// 242.024 us; speedup vs baseline: 1.1885x; 1.0962x over previous
//
#include <hip/hip_runtime.h>
#include <cstddef>
#include <cstdint>

#define T_TOK 2048
#define HD 1024
#define ID 1024
#define NE 16
#define TOPK 4
#define BM 128
#define BN 128
#define BK 32
#define MT_MAX 96
#define SLOT_CAP (MT_MAX * BM)

typedef float f32x4 __attribute__((ext_vector_type(4)));
typedef __bf16 bf16x8 __attribute__((ext_vector_type(8)));
typedef __bf16 bf16x4 __attribute__((ext_vector_type(4)));

// ---- workspace layout (bytes) ----
#define WS_TILE_E 256                                   // int[MT_MAX]
#define WS_LOGITS 4096                                  // float[2048*16]
#define WS_SLOT_TOK (WS_LOGITS + T_TOK * NE * 4)        // int[SLOT_CAP]
#define WS_SLOT_W (WS_SLOT_TOK + SLOT_CAP * 4)          // float[SLOT_CAP]
#define WS_H1 (WS_SLOT_W + SLOT_CAP * 4)                // bf16[SLOT_CAP][ID]
#define WS_XB (WS_H1 + (size_t)SLOT_CAP * ID * 2)       // bf16[T][H]
#define WS_W1B (WS_XB + (size_t)T_TOK * HD * 2)         // bf16 E*I*H
#define WS_W2B (WS_W1B + (size_t)NE * ID * HD * 2)
#define WS_W3B (WS_W2B + (size_t)NE * HD * ID * 2)
#define WS_SW1B (WS_W3B + (size_t)NE * ID * HD * 2)
#define WS_SW2B (WS_SW1B + (size_t)ID * HD * 2)
#define WS_SW3B (WS_SW2B + (size_t)HD * ID * 2)
#define WS_NEED (WS_SW3B + (size_t)ID * HD * 2)

__device__ __forceinline__ f32x4 mfma16(bf16x8 a, bf16x8 b, f32x4 c) {
  return __builtin_amdgcn_mfma_f32_16x16x32_bf16(a, b, c, 0, 0, 0);
}

__device__ __forceinline__ bf16x4 pack4(f32x4 a) {
  bf16x4 o;
  o[0] = (__bf16)a[0]; o[1] = (__bf16)a[1]; o[2] = (__bf16)a[2]; o[3] = (__bf16)a[3];
  return o;
}

// async global(16B/lane) -> LDS, linear dest (m97 pattern)
__device__ __forceinline__ void gload16(const __bf16* g, __bf16* l) {
  __builtin_amdgcn_global_load_lds(
      (const __attribute__((address_space(1))) uint32_t*)g,
      (__attribute__((address_space(3))) uint32_t*)l, 16, 0, 0);
}

// ---- fused_pre: router logits (512 blocks) + chunked cvt (2048 blocks) ----
// cvt: per block-iteration, one 2048-f32x4 (32 KB) chunk; thread t loads 8
// INDEPENDENT f32x4 at off + t + j*256 -> every load instruction is
// lane-adjacent 16B (fully coalesced 1KB/wave) AND MLP=8.  Round-9 lesson:
// 128B-per-lane unroll makes each instr touch 64 cache lines -> TA-bound.
#define W4 ((size_t)1 << 22)   // f32x4 per big weight tensor
#define S4 ((size_t)1 << 18)   // per shared weight tensor
#define X4 ((size_t)1 << 19)   // x
#define CVT4_TOTAL (3 * W4 + 3 * S4 + X4)
#define NCHUNK (CVT4_TOTAL / 2048)   // 6784; all segment bounds % 2048 == 0
#define CVT_GRID 2048
#define LOGITS_BLOCKS (T_TOK / 4)

__global__ __launch_bounds__(256) void fused_pre(
    const float* __restrict__ w1, const float* __restrict__ w2,
    const float* __restrict__ w3, const float* __restrict__ sw1,
    const float* __restrict__ sw2, const float* __restrict__ sw3,
    const float* __restrict__ x, __bf16* __restrict__ w1b,
    __bf16* __restrict__ w2b, __bf16* __restrict__ w3b,
    __bf16* __restrict__ sw1b, __bf16* __restrict__ sw2b,
    __bf16* __restrict__ sw3b, __bf16* __restrict__ xb,
    const float* __restrict__ gw, float* __restrict__ logits) {
  int tid = threadIdx.x;
  if ((int)blockIdx.x < LOGITS_BLOCKS) {
    int wv = tid >> 6;
    int lane = tid & 63;
    int tok = blockIdx.x * 4 + wv;
    int e = lane >> 2;
    int q = lane & 3;
    const float4* xr = (const float4*)(x + (size_t)tok * HD) + q * 64;
    const float4* wr = (const float4*)(gw + (size_t)e * HD) + q * 64;
    float s0 = 0.f, s1 = 0.f;
#pragma unroll 8
    for (int i = 0; i < 64; i += 2) {
      float4 a0 = xr[i], w0 = wr[i];
      float4 a1 = xr[i + 1], w1v = wr[i + 1];
      s0 += a0.x * w0.x + a0.y * w0.y + a0.z * w0.z + a0.w * w0.w;
      s1 += a1.x * w1v.x + a1.y * w1v.y + a1.z * w1v.z + a1.w * w1v.w;
    }
    float s = s0 + s1;
    s += __shfl_xor(s, 1);
    s += __shfl_xor(s, 2);
    if (q == 0) logits[(size_t)tok * NE + e] = s;
    return;
  }
  size_t b = blockIdx.x - LOGITS_BLOCKS;
  for (size_t c = b; c < NCHUNK; c += CVT_GRID) {
    size_t f = c * 2048;  // f32x4 base index of this chunk
    const float* src;
    __bf16* dst;
    size_t off;
    if (f < 3 * W4) {
      size_t t = f >> 22;
      off = f & (W4 - 1);
      src = (t == 0) ? w1 : (t == 1) ? w2 : w3;
      dst = (t == 0) ? w1b : (t == 1) ? w2b : w3b;
    } else {
      size_t j = f - 3 * W4;
      if (j < 3 * S4) {
        size_t t = j >> 18;
        off = j & (S4 - 1);
        src = (t == 0) ? sw1 : (t == 1) ? sw2 : sw3;
        dst = (t == 0) ? sw1b : (t == 1) ? sw2b : sw3b;
      } else {
        off = j - 3 * S4;
        src = x;
        dst = xb;
      }
    }
    const f32x4* p = (const f32x4*)src + off + tid;
    __bf16* q = dst + 4 * (off + tid);
    f32x4 v0 = __builtin_nontemporal_load(p);
    f32x4 v1 = __builtin_nontemporal_load(p + 256);
    f32x4 v2 = __builtin_nontemporal_load(p + 512);
    f32x4 v3 = __builtin_nontemporal_load(p + 768);
    f32x4 v4 = __builtin_nontemporal_load(p + 1024);
    f32x4 v5 = __builtin_nontemporal_load(p + 1280);
    f32x4 v6 = __builtin_nontemporal_load(p + 1536);
    f32x4 v7 = __builtin_nontemporal_load(p + 1792);
    *(bf16x4*)(q + 0 * 1024) = pack4(v0);
    *(bf16x4*)(q + 1 * 1024) = pack4(v1);
    *(bf16x4*)(q + 2 * 1024) = pack4(v2);
    *(bf16x4*)(q + 3 * 1024) = pack4(v3);
    *(bf16x4*)(q + 4 * 1024) = pack4(v4);
    *(bf16x4*)(q + 5 * 1024) = pack4(v5);
    *(bf16x4*)(q + 6 * 1024) = pack4(v6);
    *(bf16x4*)(q + 7 * 1024) = pack4(v7);
  }
}

// ------- router_finish: top-4 + softmax + scan + scatter (one block) -------
__global__ __launch_bounds__(256) void router_finish(
    const float* __restrict__ logits, const float* __restrict__ bias,
    int* __restrict__ tile_e, int* __restrict__ slot_tok,
    float* __restrict__ slot_w) {
  __shared__ int hist[NE];
  __shared__ int soff[NE + 1];
  __shared__ int fillp[NE];
  __shared__ unsigned lsel[T_TOK];
  __shared__ float4 lw4[T_TOK];

  int tid = threadIdx.x;
  if (tid < NE) { hist[tid] = 0; fillp[tid] = 0; }
  __syncthreads();

  float bb[NE];
#pragma unroll
  for (int e = 0; e < NE; ++e) bb[e] = bias[e];

  for (int j = 0; j < T_TOK / 256; ++j) {
    int t = tid + 256 * j;
    float lg[NE];
    const float4* lp = (const float4*)(logits + (size_t)t * NE);
#pragma unroll
    for (int q = 0; q < 4; ++q) {
      float4 v = lp[q];
      lg[4 * q] = v.x; lg[4 * q + 1] = v.y; lg[4 * q + 2] = v.z; lg[4 * q + 3] = v.w;
    }
    float b[NE];
#pragma unroll
    for (int e = 0; e < NE; ++e) b[e] = lg[e] + bb[e];

    int selk[TOPK];
    float raw[TOPK];
    unsigned used = 0;
#pragma unroll
    for (int k = 0; k < TOPK; ++k) {
      float best = -3.4e38f;
      int bi = 0;
#pragma unroll
      for (int e = 0; e < NE; ++e) {
        if (!((used >> e) & 1) && b[e] > best) { best = b[e]; bi = e; }
      }
      used |= (1u << bi);
      selk[k] = bi;
      raw[k] = lg[bi];
    }
    float m = raw[0];
#pragma unroll
    for (int k = 1; k < TOPK; ++k) m = fmaxf(m, raw[k]);
    float s = 0.f;
    float w[TOPK];
#pragma unroll
    for (int k = 0; k < TOPK; ++k) { w[k] = __expf(raw[k] - m); s += w[k]; }
    float inv = 1.f / s;
    lsel[t] = (unsigned)selk[0] | ((unsigned)selk[1] << 8) |
              ((unsigned)selk[2] << 16) | ((unsigned)selk[3] << 24);
    lw4[t] = make_float4(w[0] * inv, w[1] * inv, w[2] * inv, w[3] * inv);
#pragma unroll
    for (int k = 0; k < TOPK; ++k) atomicAdd(&hist[selk[k]], 1);
  }
  __syncthreads();

  if (tid == 0) {
    int o = 0;
    for (int e = 0; e < NE; ++e) { soff[e] = o; o += (hist[e] + BM - 1) & ~(BM - 1); }
    soff[NE] = o;
  }
  __syncthreads();
  int shared_base = soff[NE];
  int total = shared_base + T_TOK;
  for (int tt = tid; tt < MT_MAX; tt += 256) {
    int base = tt * BM;
    int ee = -1;
    if (base < shared_base) {
      ee = 0;
#pragma unroll
      for (int q = 1; q < NE; ++q) if (base >= soff[q]) ee = q;
    } else if (base < total) {
      ee = NE;
    }
    tile_e[tt] = ee;
  }

  for (int j = 0; j < T_TOK / 256; ++j) {
    int t = tid + 256 * j;
    unsigned ps = lsel[t];
    float4 wv = lw4[t];
    int e0 = ps & 255, e1 = (ps >> 8) & 255, e2 = (ps >> 16) & 255, e3 = ps >> 24;
    int p0 = atomicAdd(&fillp[e0], 1);
    slot_tok[soff[e0] + p0] = t; slot_w[soff[e0] + p0] = wv.x;
    int p1 = atomicAdd(&fillp[e1], 1);
    slot_tok[soff[e1] + p1] = t; slot_w[soff[e1] + p1] = wv.y;
    int p2 = atomicAdd(&fillp[e2], 1);
    slot_tok[soff[e2] + p2] = t; slot_w[soff[e2] + p2] = wv.z;
    int p3 = atomicAdd(&fillp[e3], 1);
    slot_tok[soff[e3] + p3] = t; slot_w[soff[e3] + p3] = wv.w;
  }

  for (int s = tid; s < shared_base; s += 256) {
    int e = 0;
#pragma unroll
    for (int q = 1; q < NE; ++q) if (s >= soff[q]) e = q;
    if (s >= soff[e] + hist[e]) { slot_tok[s] = -1; slot_w[s] = 0.f; }
  }
  for (int s = shared_base + tid; s < total; s += 256) {
    slot_tok[s] = s - shared_base;
    slot_w[s] = 1.0f;
  }
}

// ===== bf16 GEMMs: dbuf + COUNTED vmcnt pipeline (T3/T4) + XOR swizzle ======
// (proven round-7 structure; raw s_barrier avoids the vmcnt(0) drain)

// pass 1: h1 = silu(x w1^T) * (x w3^T).  (256,2): accs=128 regs, 3/EU spills.
__global__ __launch_bounds__(256, 2) void pass1_bf16(
    const __bf16* __restrict__ xb, const int* __restrict__ slot_tok,
    const int* __restrict__ tile_e, const __bf16* __restrict__ w1b,
    const __bf16* __restrict__ w3b, const __bf16* __restrict__ sw1b,
    const __bf16* __restrict__ sw3b, __bf16* __restrict__ h1) {
  int mt = blockIdx.y;
  int e = tile_e[mt];
  if (e < 0) return;
  int n0 = blockIdx.x * BN;
  int m0 = mt * BM;

  const __bf16* wg = (e == NE) ? sw1b : w1b + (size_t)e * ID * HD;
  const __bf16* wu = (e == NE) ? sw3b : w3b + (size_t)e * ID * HD;

  __shared__ __align__(16) __bf16 As[2][BM * BK];
  __shared__ __align__(16) __bf16 Bg[2][BN * BK];
  __shared__ __align__(16) __bf16 Bu[2][BN * BK];

  int tid = threadIdx.x;
  int r0 = tid >> 2, r1 = r0 + 64;
  int c8 = ((tid & 3) ^ ((r0 >> 1) & 3)) * 8;  // pre-swizzled global chunk
  int tok0 = slot_tok[m0 + r0]; if (tok0 < 0) tok0 = 0;
  int tok1 = slot_tok[m0 + r1]; if (tok1 < 0) tok1 = 0;
  const __bf16* gA0 = xb + (size_t)tok0 * HD + c8;
  const __bf16* gA1 = xb + (size_t)tok1 * HD + c8;
  const __bf16* gG0 = wg + (size_t)(n0 + r0) * HD + c8;
  const __bf16* gG1 = wg + (size_t)(n0 + r1) * HD + c8;
  const __bf16* gU0 = wu + (size_t)(n0 + r0) * HD + c8;
  const __bf16* gU1 = wu + (size_t)(n0 + r1) * HD + c8;

  int wave = tid >> 6, lane = tid & 63;
  int wm = (wave >> 1) * 64, wn = (wave & 1) * 64;
  int l16 = lane & 15, kch = lane >> 4;
  int kk8 = (kch ^ ((l16 >> 1) & 3)) * 8;  // swizzled read chunk

  f32x4 accg[4][4] = {};
  f32x4 accu[4][4] = {};

  auto stage = [&](int B, int k0) {
    gload16(gA0 + k0, &As[B][(size_t)tid * 8]);
    gload16(gA1 + k0, &As[B][(size_t)(tid + 256) * 8]);
    gload16(gG0 + k0, &Bg[B][(size_t)tid * 8]);
    gload16(gG1 + k0, &Bg[B][(size_t)(tid + 256) * 8]);
    gload16(gU0 + k0, &Bu[B][(size_t)tid * 8]);
    gload16(gU1 + k0, &Bu[B][(size_t)(tid + 256) * 8]);
  };
  auto body = [&](int B) {
    bf16x8 af[4], gf[4], uf[4];
#pragma unroll
    for (int i = 0; i < 4; ++i) {
      af[i] = *(const bf16x8*)(&As[B][(wm + i * 16 + l16) * BK + kk8]);
      gf[i] = *(const bf16x8*)(&Bg[B][(wn + i * 16 + l16) * BK + kk8]);
      uf[i] = *(const bf16x8*)(&Bu[B][(wn + i * 16 + l16) * BK + kk8]);
    }
    asm volatile("s_waitcnt lgkmcnt(0)" ::: "memory");
    __builtin_amdgcn_s_barrier();            // buffer free for next stage
    __builtin_amdgcn_sched_barrier(0);       // rule #18
#pragma unroll
    for (int mi = 0; mi < 4; ++mi)
#pragma unroll
      for (int ni = 0; ni < 4; ++ni) {
        accg[mi][ni] = mfma16(af[mi], gf[ni], accg[mi][ni]);
        accu[mi][ni] = mfma16(af[mi], uf[ni], accu[mi][ni]);
      }
  };

  stage(0, 0);
#pragma unroll 1
  for (int k = 0; k < HD / BK - 1; ++k) {
    int cur = k & 1;
    stage(cur ^ 1, (k + 1) * BK);            // 6 loads stay in flight
    asm volatile("s_waitcnt vmcnt(6)" ::: "memory");
    __builtin_amdgcn_s_barrier();
    __builtin_amdgcn_sched_barrier(0);
    body(cur);
  }
  asm volatile("s_waitcnt vmcnt(0)" ::: "memory");
  __builtin_amdgcn_s_barrier();
  __builtin_amdgcn_sched_barrier(0);
  body((HD / BK - 1) & 1);

#pragma unroll
  for (int mi = 0; mi < 4; ++mi) {
#pragma unroll
    for (int ni = 0; ni < 4; ++ni) {
#pragma unroll
      for (int j = 0; j < 4; ++j) {
        int row = m0 + wm + mi * 16 + kch * 4 + j;
        int col = n0 + wn + ni * 16 + l16;
        float g = accg[mi][ni][j];
        float u = accu[mi][ni][j];
        float hv = (g / (1.f + __expf(-g))) * u;
        h1[(size_t)row * ID + col] = (__bf16)hv;
      }
    }
  }
}

// pass 2: out += g * (h1 w2^T)
__global__ __launch_bounds__(256, 3) void pass2_bf16(
    const __bf16* __restrict__ h1, const int* __restrict__ slot_tok,
    const float* __restrict__ slot_w, const int* __restrict__ tile_e,
    const __bf16* __restrict__ w2b, const __bf16* __restrict__ sw2b,
    float* __restrict__ out) {
  int mt = blockIdx.y;
  int e = tile_e[mt];
  if (e < 0) return;
  int n0 = blockIdx.x * BN;
  int m0 = mt * BM;

  const __bf16* wd = (e == NE) ? sw2b : w2b + (size_t)e * HD * ID;

  __shared__ __align__(16) __bf16 As[2][BM * BK];
  __shared__ __align__(16) __bf16 Bs[2][BN * BK];

  int tid = threadIdx.x;
  int r0 = tid >> 2, r1 = r0 + 64;
  int c8 = ((tid & 3) ^ ((r0 >> 1) & 3)) * 8;
  const __bf16* gA0 = h1 + (size_t)(m0 + r0) * ID + c8;
  const __bf16* gA1 = h1 + (size_t)(m0 + r1) * ID + c8;
  const __bf16* gB0 = wd + (size_t)(n0 + r0) * ID + c8;
  const __bf16* gB1 = wd + (size_t)(n0 + r1) * ID + c8;

  int wave = tid >> 6, lane = tid & 63;
  int wm = (wave >> 1) * 64, wn = (wave & 1) * 64;
  int l16 = lane & 15, kch = lane >> 4;
  int kk8 = (kch ^ ((l16 >> 1) & 3)) * 8;

  f32x4 acc[4][4] = {};

  auto stage = [&](int B, int k0) {
    gload16(gA0 + k0, &As[B][(size_t)tid * 8]);
    gload16(gA1 + k0, &As[B][(size_t)(tid + 256) * 8]);
    gload16(gB0 + k0, &Bs[B][(size_t)tid * 8]);
    gload16(gB1 + k0, &Bs[B][(size_t)(tid + 256) * 8]);
  };
  auto body = [&](int B) {
    bf16x8 af[4], bf[4];
#pragma unroll
    for (int i = 0; i < 4; ++i) {
      af[i] = *(const bf16x8*)(&As[B][(wm + i * 16 + l16) * BK + kk8]);
      bf[i] = *(const bf16x8*)(&Bs[B][(wn + i * 16 + l16) * BK + kk8]);
    }
    asm volatile("s_waitcnt lgkmcnt(0)" ::: "memory");
    __builtin_amdgcn_s_barrier();
    __builtin_amdgcn_sched_barrier(0);
#pragma unroll
    for (int mi = 0; mi < 4; ++mi)
#pragma unroll
      for (int ni = 0; ni < 4; ++ni)
        acc[mi][ni] = mfma16(af[mi], bf[ni], acc[mi][ni]);
  };

  stage(0, 0);
#pragma unroll 1
  for (int k = 0; k < ID / BK - 1; ++k) {
    int cur = k & 1;
    stage(cur ^ 1, (k + 1) * BK);
    asm volatile("s_waitcnt vmcnt(4)" ::: "memory");
    __builtin_amdgcn_s_barrier();
    __builtin_amdgcn_sched_barrier(0);
    body(cur);
  }
  asm volatile("s_waitcnt vmcnt(0)" ::: "memory");
  __builtin_amdgcn_s_barrier();
  __builtin_amdgcn_sched_barrier(0);
  body((ID / BK - 1) & 1);

#pragma unroll
  for (int mi = 0; mi < 4; ++mi) {
#pragma unroll
    for (int j = 0; j < 4; ++j) {
      int row = m0 + wm + mi * 16 + kch * 4 + j;
      int token = slot_tok[row];
      if (token < 0) continue;
      float wgt = slot_w[row];
#pragma unroll
      for (int ni = 0; ni < 4; ++ni) {
        int col = n0 + wn + ni * 16 + l16;
        atomicAdd(out + (size_t)token * HD + col, wgt * acc[mi][ni][j]);
      }
    }
  }
}

// ---------------- launcher ----------------
extern "C" void kernel_launch(void* const* d_in, const int* in_sizes, int n_in,
                              void* d_out, int out_size, void* d_ws, size_t ws_size,
                              hipStream_t stream) {
  const float* x = (const float*)d_in[0];
  const float* gate_w = (const float*)d_in[1];
  const float* ebias = (const float*)d_in[2];
  const float* w1 = (const float*)d_in[3];
  const float* w2 = (const float*)d_in[4];
  const float* w3 = (const float*)d_in[5];
  const float* sw1 = (const float*)d_in[6];
  const float* sw2 = (const float*)d_in[7];
  const float* sw3 = (const float*)d_in[8];
  float* out = (float*)d_out;

  char* ws = (char*)d_ws;
  int* tile_e = (int*)(ws + WS_TILE_E);
  float* logits = (float*)(ws + WS_LOGITS);
  int* slot_tok = (int*)(ws + WS_SLOT_TOK);
  float* slot_w = (float*)(ws + WS_SLOT_W);
  __bf16* h1 = (__bf16*)(ws + WS_H1);
  __bf16* xb = (__bf16*)(ws + WS_XB);
  __bf16* w1b = (__bf16*)(ws + WS_W1B);
  __bf16* w2b = (__bf16*)(ws + WS_W2B);
  __bf16* w3b = (__bf16*)(ws + WS_W3B);
  __bf16* sw1b = (__bf16*)(ws + WS_SW1B);
  __bf16* sw2b = (__bf16*)(ws + WS_SW2B);
  __bf16* sw3b = (__bf16*)(ws + WS_SW3B);

  hipMemsetAsync(d_out, 0, (size_t)T_TOK * HD * sizeof(float), stream);

  fused_pre<<<LOGITS_BLOCKS + CVT_GRID, 256, 0, stream>>>(
      w1, w2, w3, sw1, sw2, sw3, x, w1b, w2b, w3b, sw1b, sw2b, sw3b, xb,
      gate_w, logits);
  router_finish<<<1, 256, 0, stream>>>(logits, ebias, tile_e, slot_tok, slot_w);

  pass1_bf16<<<dim3(ID / BN, MT_MAX), 256, 0, stream>>>(
      xb, slot_tok, tile_e, w1b, w3b, sw1b, sw3b, h1);
  pass2_bf16<<<dim3(HD / BN, MT_MAX), 256, 0, stream>>>(
      h1, slot_tok, slot_w, tile_e, w2b, sw2b, out);
}

// Round 11
// 223.842 us; speedup vs baseline: 1.2851x; 1.0812x over previous
//
#include <hip/hip_runtime.h>
#include <cstddef>
#include <cstdint>

#define T_TOK 2048
#define HD 1024
#define ID 1024
#define NE 16
#define TOPK 4
#define BM 128
#define BN 128
#define BK 32
#define MT_MAX 96
#define SLOT_CAP (MT_MAX * BM)

typedef float f32x4 __attribute__((ext_vector_type(4)));
typedef __bf16 bf16x8 __attribute__((ext_vector_type(8)));
typedef __bf16 bf16x4 __attribute__((ext_vector_type(4)));

// ---- workspace layout (bytes) ----
#define WS_TILE_E 256                                   // int[MT_MAX]
#define WS_LOGITS 4096                                  // float[2048*16]
#define WS_SLOT_TOK (WS_LOGITS + T_TOK * NE * 4)        // int[SLOT_CAP]
#define WS_SLOT_W (WS_SLOT_TOK + SLOT_CAP * 4)          // float[SLOT_CAP]
#define WS_H1 (WS_SLOT_W + SLOT_CAP * 4)                // bf16[SLOT_CAP][ID]
#define WS_XB (WS_H1 + (size_t)SLOT_CAP * ID * 2)       // bf16[T][H]

__device__ __forceinline__ f32x4 mfma16(bf16x8 a, bf16x8 b, f32x4 c) {
  return __builtin_amdgcn_mfma_f32_16x16x32_bf16(a, b, c, 0, 0, 0);
}

__device__ __forceinline__ bf16x8 pack8(f32x4 a, f32x4 b) {
  bf16x8 o;
  o[0] = (__bf16)a[0]; o[1] = (__bf16)a[1]; o[2] = (__bf16)a[2]; o[3] = (__bf16)a[3];
  o[4] = (__bf16)b[0]; o[5] = (__bf16)b[1]; o[6] = (__bf16)b[2]; o[7] = (__bf16)b[3];
  return o;
}

__device__ __forceinline__ bf16x4 pack4(f32x4 a) {
  bf16x4 o;
  o[0] = (__bf16)a[0]; o[1] = (__bf16)a[1]; o[2] = (__bf16)a[2]; o[3] = (__bf16)a[3];
  return o;
}

// async global(16B/lane) -> LDS, linear dest (m97 pattern); dtype-agnostic
__device__ __forceinline__ void gload16(const __bf16* g, __bf16* l) {
  __builtin_amdgcn_global_load_lds(
      (const __attribute__((address_space(1))) uint32_t*)g,
      (__attribute__((address_space(3))) uint32_t*)l, 16, 0, 0);
}
__device__ __forceinline__ void gload16f(const float* g, float* l) {
  __builtin_amdgcn_global_load_lds(
      (const __attribute__((address_space(1))) uint32_t*)g,
      (__attribute__((address_space(3))) uint32_t*)l, 16, 0, 0);
}

// ---- fused_pre: router logits (512 blocks) + x cvt (256 blocks) -----------
// Weights are NOT converted anymore: both GEMM passes stage fp32 panels
// directly into LDS and convert after the ds_read (post-LDS cvt).
#define LOGITS_BLOCKS (T_TOK / 4)
#define XCHUNKS 256   // (T*H/4) f32x4 / 2048 per chunk

__global__ __launch_bounds__(256) void fused_pre(
    const float* __restrict__ x, const float* __restrict__ gw,
    __bf16* __restrict__ xb, float* __restrict__ logits) {
  int tid = threadIdx.x;
  if ((int)blockIdx.x < LOGITS_BLOCKS) {
    int wv = tid >> 6;
    int lane = tid & 63;
    int tok = blockIdx.x * 4 + wv;
    int e = lane >> 2;
    int q = lane & 3;
    const float4* xr = (const float4*)(x + (size_t)tok * HD) + q * 64;
    const float4* wr = (const float4*)(gw + (size_t)e * HD) + q * 64;
    float s0 = 0.f, s1 = 0.f;
#pragma unroll 8
    for (int i = 0; i < 64; i += 2) {
      float4 a0 = xr[i], w0 = wr[i];
      float4 a1 = xr[i + 1], w1v = wr[i + 1];
      s0 += a0.x * w0.x + a0.y * w0.y + a0.z * w0.z + a0.w * w0.w;
      s1 += a1.x * w1v.x + a1.y * w1v.y + a1.z * w1v.z + a1.w * w1v.w;
    }
    float s = s0 + s1;
    s += __shfl_xor(s, 1);
    s += __shfl_xor(s, 2);
    if (q == 0) logits[(size_t)tok * NE + e] = s;
    return;
  }
  // x cvt: one 2048-f32x4 chunk per block, lane-adjacent 16B, MLP=8
  size_t f = (size_t)(blockIdx.x - LOGITS_BLOCKS) * 2048;
  const f32x4* p = (const f32x4*)x + f + tid;
  __bf16* q = xb + 4 * (f + tid);
  f32x4 v0 = p[0], v1 = p[256], v2 = p[512], v3 = p[768];
  f32x4 v4 = p[1024], v5 = p[1280], v6 = p[1536], v7 = p[1792];
  *(bf16x4*)(q + 0 * 1024) = pack4(v0);
  *(bf16x4*)(q + 1 * 1024) = pack4(v1);
  *(bf16x4*)(q + 2 * 1024) = pack4(v2);
  *(bf16x4*)(q + 3 * 1024) = pack4(v3);
  *(bf16x4*)(q + 4 * 1024) = pack4(v4);
  *(bf16x4*)(q + 5 * 1024) = pack4(v5);
  *(bf16x4*)(q + 6 * 1024) = pack4(v6);
  *(bf16x4*)(q + 7 * 1024) = pack4(v7);
}

// ------- router_finish: top-4 + softmax + scan + scatter (one block) -------
__global__ __launch_bounds__(256) void router_finish(
    const float* __restrict__ logits, const float* __restrict__ bias,
    int* __restrict__ tile_e, int* __restrict__ slot_tok,
    float* __restrict__ slot_w) {
  __shared__ int hist[NE];
  __shared__ int soff[NE + 1];
  __shared__ int fillp[NE];
  __shared__ unsigned lsel[T_TOK];
  __shared__ float4 lw4[T_TOK];

  int tid = threadIdx.x;
  if (tid < NE) { hist[tid] = 0; fillp[tid] = 0; }
  __syncthreads();

  float bb[NE];
#pragma unroll
  for (int e = 0; e < NE; ++e) bb[e] = bias[e];

  for (int j = 0; j < T_TOK / 256; ++j) {
    int t = tid + 256 * j;
    float lg[NE];
    const float4* lp = (const float4*)(logits + (size_t)t * NE);
#pragma unroll
    for (int q = 0; q < 4; ++q) {
      float4 v = lp[q];
      lg[4 * q] = v.x; lg[4 * q + 1] = v.y; lg[4 * q + 2] = v.z; lg[4 * q + 3] = v.w;
    }
    float b[NE];
#pragma unroll
    for (int e = 0; e < NE; ++e) b[e] = lg[e] + bb[e];

    int selk[TOPK];
    float raw[TOPK];
    unsigned used = 0;
#pragma unroll
    for (int k = 0; k < TOPK; ++k) {
      float best = -3.4e38f;
      int bi = 0;
#pragma unroll
      for (int e = 0; e < NE; ++e) {
        if (!((used >> e) & 1) && b[e] > best) { best = b[e]; bi = e; }
      }
      used |= (1u << bi);
      selk[k] = bi;
      raw[k] = lg[bi];
    }
    float m = raw[0];
#pragma unroll
    for (int k = 1; k < TOPK; ++k) m = fmaxf(m, raw[k]);
    float s = 0.f;
    float w[TOPK];
#pragma unroll
    for (int k = 0; k < TOPK; ++k) { w[k] = __expf(raw[k] - m); s += w[k]; }
    float inv = 1.f / s;
    lsel[t] = (unsigned)selk[0] | ((unsigned)selk[1] << 8) |
              ((unsigned)selk[2] << 16) | ((unsigned)selk[3] << 24);
    lw4[t] = make_float4(w[0] * inv, w[1] * inv, w[2] * inv, w[3] * inv);
#pragma unroll
    for (int k = 0; k < TOPK; ++k) atomicAdd(&hist[selk[k]], 1);
  }
  __syncthreads();

  if (tid == 0) {
    int o = 0;
    for (int e = 0; e < NE; ++e) { soff[e] = o; o += (hist[e] + BM - 1) & ~(BM - 1); }
    soff[NE] = o;
  }
  __syncthreads();
  int shared_base = soff[NE];
  int total = shared_base + T_TOK;
  for (int tt = tid; tt < MT_MAX; tt += 256) {
    int base = tt * BM;
    int ee = -1;
    if (base < shared_base) {
      ee = 0;
#pragma unroll
      for (int q = 1; q < NE; ++q) if (base >= soff[q]) ee = q;
    } else if (base < total) {
      ee = NE;
    }
    tile_e[tt] = ee;
  }

  for (int j = 0; j < T_TOK / 256; ++j) {
    int t = tid + 256 * j;
    unsigned ps = lsel[t];
    float4 wv = lw4[t];
    int e0 = ps & 255, e1 = (ps >> 8) & 255, e2 = (ps >> 16) & 255, e3 = ps >> 24;
    int p0 = atomicAdd(&fillp[e0], 1);
    slot_tok[soff[e0] + p0] = t; slot_w[soff[e0] + p0] = wv.x;
    int p1 = atomicAdd(&fillp[e1], 1);
    slot_tok[soff[e1] + p1] = t; slot_w[soff[e1] + p1] = wv.y;
    int p2 = atomicAdd(&fillp[e2], 1);
    slot_tok[soff[e2] + p2] = t; slot_w[soff[e2] + p2] = wv.z;
    int p3 = atomicAdd(&fillp[e3], 1);
    slot_tok[soff[e3] + p3] = t; slot_w[soff[e3] + p3] = wv.w;
  }

  for (int s = tid; s < shared_base; s += 256) {
    int e = 0;
#pragma unroll
    for (int q = 1; q < NE; ++q) if (s >= soff[q]) e = q;
    if (s >= soff[e] + hist[e]) { slot_tok[s] = -1; slot_w[s] = 0.f; }
  }
  for (int s = shared_base + tid; s < total; s += 256) {
    slot_tok[s] = s - shared_base;
    slot_w[s] = 1.0f;
  }
}

// ===== GEMMs: counted-vmcnt pipeline + fp32-B direct staging ================
// B panels stage as RAW FP32 via global_load_lds (no reg round-trip, no
// vmcnt(0) in loop -- unlike round-8's failed reg-staging).  ds_read two
// f32x4 per fragment, cvt to bf16x8 in-register before MFMA.  fp32 LDS rows
// = 8 x 16B chunks; slot s of row r holds global chunk s^(r&7) (both-sides
// XOR swizzle -> 2-way conflicts = free).

// pass 1: h1 = silu(x w1^T) * (x w3^T); LDS 80KB -> 2 blocks/CU (=160KB).
// (256,2): dual acc = 128 regs; 3/EU would spill (round-5 lesson).
__global__ __launch_bounds__(256, 2) void pass1_bf16(
    const __bf16* __restrict__ xb, const int* __restrict__ slot_tok,
    const int* __restrict__ tile_e, const float* __restrict__ w1,
    const float* __restrict__ w3, const float* __restrict__ sw1,
    const float* __restrict__ sw3, __bf16* __restrict__ h1) {
  int mt = blockIdx.y;
  int e = tile_e[mt];
  if (e < 0) return;
  int n0 = blockIdx.x * BN;
  int m0 = mt * BM;

  const float* wg = (e == NE) ? sw1 : w1 + (size_t)e * ID * HD;
  const float* wu = (e == NE) ? sw3 : w3 + (size_t)e * ID * HD;

  __shared__ __align__(16) __bf16 As[2][BM * BK];   // 16 KB
  __shared__ __align__(16) float BgF[2][BN * BK];   // 32 KB
  __shared__ __align__(16) float BuF[2][BN * BK];   // 32 KB

  int tid = threadIdx.x;
  // A staging (bf16, swizzled global source, linear LDS dest)
  int r0 = tid >> 2, r1 = r0 + 64;
  int c8 = ((tid & 3) ^ ((r0 >> 1) & 3)) * 8;
  int tok0 = slot_tok[m0 + r0]; if (tok0 < 0) tok0 = 0;
  int tok1 = slot_tok[m0 + r1]; if (tok1 < 0) tok1 = 0;
  const __bf16* gA0 = xb + (size_t)tok0 * HD + c8;
  const __bf16* gA1 = xb + (size_t)tok1 * HD + c8;

  // B fp32 staging: 1024 chunk-slots/panel (128 rows x 8); thread t covers
  // slots t+j*256; slot id -> row=id>>3, phys chunk s=id&7 holds global
  // chunk s^(row&7).
  const float* srcG[4];
  const float* srcU[4];
  int ldst[4];
#pragma unroll
  for (int j = 0; j < 4; ++j) {
    int id = tid + j * 256;
    int r = id >> 3, s = id & 7;
    int go = (s ^ (r & 7)) << 2;
    srcG[j] = wg + (size_t)(n0 + r) * HD + go;
    srcU[j] = wu + (size_t)(n0 + r) * HD + go;
    ldst[j] = id * 4;
  }

  int wave = tid >> 6, lane = tid & 63;
  int wm = (wave >> 1) * 64, wn = (wave & 1) * 64;
  int l16 = lane & 15, kch = lane >> 4;
  int kk8 = (kch ^ ((l16 >> 1) & 3)) * 8;     // A-side swizzled chunk
  int sw = l16 & 7;
  int cB0 = ((2 * kch) ^ sw) * 4;             // B-side swizzled f32 chunks
  int cB1 = ((2 * kch + 1) ^ sw) * 4;

  f32x4 accg[4][4] = {};
  f32x4 accu[4][4] = {};

  auto stage = [&](int B, int k0) {           // 10 loads total
    gload16(gA0 + k0, &As[B][(size_t)tid * 8]);
    gload16(gA1 + k0, &As[B][(size_t)(tid + 256) * 8]);
#pragma unroll
    for (int j = 0; j < 4; ++j) {
      gload16f(srcG[j] + k0, &BgF[B][ldst[j]]);
      gload16f(srcU[j] + k0, &BuF[B][ldst[j]]);
    }
  };
  auto body = [&](int B) {
    bf16x8 af[4], gf[4], uf[4];
#pragma unroll
    for (int i = 0; i < 4; ++i)
      af[i] = *(const bf16x8*)(&As[B][(wm + i * 16 + l16) * BK + kk8]);
#pragma unroll
    for (int i = 0; i < 4; ++i) {
      int rb = (wn + i * 16 + l16) * BK;
      f32x4 ga = *(const f32x4*)(&BgF[B][rb + cB0]);
      f32x4 gb = *(const f32x4*)(&BgF[B][rb + cB1]);
      gf[i] = pack8(ga, gb);
      f32x4 ua = *(const f32x4*)(&BuF[B][rb + cB0]);
      f32x4 ub = *(const f32x4*)(&BuF[B][rb + cB1]);
      uf[i] = pack8(ua, ub);
    }
    asm volatile("s_waitcnt lgkmcnt(0)" ::: "memory");
    __builtin_amdgcn_s_barrier();            // buffer free for next stage
    __builtin_amdgcn_sched_barrier(0);       // rule #18
#pragma unroll
    for (int mi = 0; mi < 4; ++mi)
#pragma unroll
      for (int ni = 0; ni < 4; ++ni) {
        accg[mi][ni] = mfma16(af[mi], gf[ni], accg[mi][ni]);
        accu[mi][ni] = mfma16(af[mi], uf[ni], accu[mi][ni]);
      }
  };

  stage(0, 0);
#pragma unroll 1
  for (int k = 0; k < HD / BK - 1; ++k) {
    int cur = k & 1;
    stage(cur ^ 1, (k + 1) * BK);            // 10 loads stay in flight
    asm volatile("s_waitcnt vmcnt(10)" ::: "memory");
    __builtin_amdgcn_s_barrier();
    __builtin_amdgcn_sched_barrier(0);
    body(cur);
  }
  asm volatile("s_waitcnt vmcnt(0)" ::: "memory");
  __builtin_amdgcn_s_barrier();
  __builtin_amdgcn_sched_barrier(0);
  body((HD / BK - 1) & 1);

#pragma unroll
  for (int mi = 0; mi < 4; ++mi) {
#pragma unroll
    for (int ni = 0; ni < 4; ++ni) {
#pragma unroll
      for (int j = 0; j < 4; ++j) {
        int row = m0 + wm + mi * 16 + kch * 4 + j;
        int col = n0 + wn + ni * 16 + l16;
        float g = accg[mi][ni][j];
        float u = accu[mi][ni][j];
        float hv = (g / (1.f + __expf(-g))) * u;
        h1[(size_t)row * ID + col] = (__bf16)hv;
      }
    }
  }
}

// pass 2: out += g * (h1 w2^T); A bf16 (h1), B fp32 (w2).  LDS 48KB.
__global__ __launch_bounds__(256, 3) void pass2_bf16(
    const __bf16* __restrict__ h1, const int* __restrict__ slot_tok,
    const float* __restrict__ slot_w, const int* __restrict__ tile_e,
    const float* __restrict__ w2, const float* __restrict__ sw2,
    float* __restrict__ out) {
  int mt = blockIdx.y;
  int e = tile_e[mt];
  if (e < 0) return;
  int n0 = blockIdx.x * BN;
  int m0 = mt * BM;

  const float* wd = (e == NE) ? sw2 : w2 + (size_t)e * HD * ID;

  __shared__ __align__(16) __bf16 As[2][BM * BK];   // 16 KB
  __shared__ __align__(16) float BF[2][BN * BK];    // 32 KB

  int tid = threadIdx.x;
  int r0 = tid >> 2, r1 = r0 + 64;
  int c8 = ((tid & 3) ^ ((r0 >> 1) & 3)) * 8;
  const __bf16* gA0 = h1 + (size_t)(m0 + r0) * ID + c8;
  const __bf16* gA1 = h1 + (size_t)(m0 + r1) * ID + c8;

  const float* srcB[4];
  int ldst[4];
#pragma unroll
  for (int j = 0; j < 4; ++j) {
    int id = tid + j * 256;
    int r = id >> 3, s = id & 7;
    int go = (s ^ (r & 7)) << 2;
    srcB[j] = wd + (size_t)(n0 + r) * ID + go;
    ldst[j] = id * 4;
  }

  int wave = tid >> 6, lane = tid & 63;
  int wm = (wave >> 1) * 64, wn = (wave & 1) * 64;
  int l16 = lane & 15, kch = lane >> 4;
  int kk8 = (kch ^ ((l16 >> 1) & 3)) * 8;
  int sw = l16 & 7;
  int cB0 = ((2 * kch) ^ sw) * 4;
  int cB1 = ((2 * kch + 1) ^ sw) * 4;

  f32x4 acc[4][4] = {};

  auto stage = [&](int B, int k0) {           // 6 loads total
    gload16(gA0 + k0, &As[B][(size_t)tid * 8]);
    gload16(gA1 + k0, &As[B][(size_t)(tid + 256) * 8]);
#pragma unroll
    for (int j = 0; j < 4; ++j) gload16f(srcB[j] + k0, &BF[B][ldst[j]]);
  };
  auto body = [&](int B) {
    bf16x8 af[4], bf[4];
#pragma unroll
    for (int i = 0; i < 4; ++i)
      af[i] = *(const bf16x8*)(&As[B][(wm + i * 16 + l16) * BK + kk8]);
#pragma unroll
    for (int i = 0; i < 4; ++i) {
      int rb = (wn + i * 16 + l16) * BK;
      f32x4 ba = *(const f32x4*)(&BF[B][rb + cB0]);
      f32x4 bb = *(const f32x4*)(&BF[B][rb + cB1]);
      bf[i] = pack8(ba, bb);
    }
    asm volatile("s_waitcnt lgkmcnt(0)" ::: "memory");
    __builtin_amdgcn_s_barrier();
    __builtin_amdgcn_sched_barrier(0);
#pragma unroll
    for (int mi = 0; mi < 4; ++mi)
#pragma unroll
      for (int ni = 0; ni < 4; ++ni)
        acc[mi][ni] = mfma16(af[mi], bf[ni], acc[mi][ni]);
  };

  stage(0, 0);
#pragma unroll 1
  for (int k = 0; k < ID / BK - 1; ++k) {
    int cur = k & 1;
    stage(cur ^ 1, (k + 1) * BK);
    asm volatile("s_waitcnt vmcnt(6)" ::: "memory");
    __builtin_amdgcn_s_barrier();
    __builtin_amdgcn_sched_barrier(0);
    body(cur);
  }
  asm volatile("s_waitcnt vmcnt(0)" ::: "memory");
  __builtin_amdgcn_s_barrier();
  __builtin_amdgcn_sched_barrier(0);
  body((ID / BK - 1) & 1);

#pragma unroll
  for (int mi = 0; mi < 4; ++mi) {
#pragma unroll
    for (int j = 0; j < 4; ++j) {
      int row = m0 + wm + mi * 16 + kch * 4 + j;
      int token = slot_tok[row];
      if (token < 0) continue;
      float wgt = slot_w[row];
#pragma unroll
      for (int ni = 0; ni < 4; ++ni) {
        int col = n0 + wn + ni * 16 + l16;
        atomicAdd(out + (size_t)token * HD + col, wgt * acc[mi][ni][j]);
      }
    }
  }
}

// ---------------- launcher ----------------
extern "C" void kernel_launch(void* const* d_in, const int* in_sizes, int n_in,
                              void* d_out, int out_size, void* d_ws, size_t ws_size,
                              hipStream_t stream) {
  const float* x = (const float*)d_in[0];
  const float* gate_w = (const float*)d_in[1];
  const float* ebias = (const float*)d_in[2];
  const float* w1 = (const float*)d_in[3];
  const float* w2 = (const float*)d_in[4];
  const float* w3 = (const float*)d_in[5];
  const float* sw1 = (const float*)d_in[6];
  const float* sw2 = (const float*)d_in[7];
  const float* sw3 = (const float*)d_in[8];
  float* out = (float*)d_out;

  char* ws = (char*)d_ws;
  int* tile_e = (int*)(ws + WS_TILE_E);
  float* logits = (float*)(ws + WS_LOGITS);
  int* slot_tok = (int*)(ws + WS_SLOT_TOK);
  float* slot_w = (float*)(ws + WS_SLOT_W);
  __bf16* h1 = (__bf16*)(ws + WS_H1);
  __bf16* xb = (__bf16*)(ws + WS_XB);

  hipMemsetAsync(d_out, 0, (size_t)T_TOK * HD * sizeof(float), stream);

  fused_pre<<<LOGITS_BLOCKS + XCHUNKS, 256, 0, stream>>>(x, gate_w, xb, logits);
  router_finish<<<1, 256, 0, stream>>>(logits, ebias, tile_e, slot_tok, slot_w);

  pass1_bf16<<<dim3(ID / BN, MT_MAX), 256, 0, stream>>>(
      xb, slot_tok, tile_e, w1, w3, sw1, sw3, h1);
  pass2_bf16<<<dim3(HD / BN, MT_MAX), 256, 0, stream>>>(
      h1, slot_tok, slot_w, tile_e, w2, sw2, out);
}